// Round 21
// baseline (312.271 us; speedup 1.0000x reference)
//
#include <hip/hip_runtime.h>

#define SLOPE 0.01f
#define SLOT  14336

typedef __attribute__((ext_vector_type(8))) short short8;
typedef __attribute__((ext_vector_type(4))) float f32x4;
typedef __attribute__((ext_vector_type(2))) float f32x2;
typedef unsigned short u16;
typedef unsigned int u32;
typedef unsigned char u8;

#define F8SCALE 16.0f
#define F8INV   0.0625f

__device__ __forceinline__ float lrelu(float v) { return v >= 0.0f ? v : SLOPE * v; }

__device__ __forceinline__ u16 f2bf(float f) {
  u32 u = __float_as_uint(f);
  return (u16)((u + 0x7FFF + ((u >> 16) & 1)) >> 16);
}
__device__ __forceinline__ float bf2f(u16 h) {
  return __uint_as_float(((u32)h) << 16);
}
__device__ __forceinline__ u8 f2f8(float v) {
  return (u8)__builtin_amdgcn_cvt_pk_fp8_f32(v, v, 0, false);
}
__device__ __forceinline__ void accf8p(f32x2* acc, u32 w) {
  acc[0] += __builtin_amdgcn_cvt_pk_f32_fp8(w, false);
  acc[1] += __builtin_amdgcn_cvt_pk_f32_fp8(w, true);
}
__device__ __forceinline__ void setf8p(f32x2* acc, u32 w) {
  acc[0] = __builtin_amdgcn_cvt_pk_f32_fp8(w, false);
  acc[1] = __builtin_amdgcn_cvt_pk_f32_fp8(w, true);
}

// ---- one-shot W pack (all 5 weights) + zero misc ----
__global__ __launch_bounds__(256) void pack_all(
    const float* __restrict__ W0, const float* __restrict__ W1, const float* __restrict__ W2,
    const float* __restrict__ W3, const float* __restrict__ W4,
    u16* __restrict__ H0, u16* __restrict__ L0, u16* __restrict__ H1, u16* __restrict__ L1,
    u16* __restrict__ H2, u16* __restrict__ L2, u16* __restrict__ H3, u16* __restrict__ L3,
    u16* __restrict__ H4, u16* __restrict__ L4, int* __restrict__ misc)
{
  const int g = blockIdx.x * 256 + threadIdx.x;
  if (g < 2304) misc[g] = 0;
  int t = g;
  const float* W; u16* hi; u16* lo; int K, C;
  if (t < 1024)      { W = W0; hi = H0; lo = L0; K = 64;  C = 128; }
  else if (t < 3072) { W = W1; hi = H1; lo = L1; K = 128; C = 128; t -= 1024; }
  else if (t < 5120) { W = W2; hi = H2; lo = L2; K = 128; C = 128; t -= 3072; }
  else if (t < 7168) { W = W3; hi = H3; lo = L3; K = 128; C = 128; t -= 5120; }
  else               { W = W4; hi = H4; lo = L4; K = 128; C = 64;  t -= 7168; }
  const int KS = K / 32;
  int l = t & 63;
  int rest = t >> 6;
  int ks = rest % KS;
  int ct = rest / KS;
  int k0 = ks * 32 + (l >> 4) * 8;
  int c  = ct * 16 + (l & 15);
  short8 hv, lv;
  #pragma unroll
  for (int b = 0; b < 8; ++b) {
    float v = W[(size_t)(k0 + b) * C + c];
    u16 h = f2bf(v);
    hv[b] = (short)h;
    lv[b] = (short)f2bf(v - bf2f(h));
  }
  ((short8*)hi)[t] = hv;
  ((short8*)lo)[t] = lv;
}

// ---- MERGED: bin_pass || refine_fused ----
__global__ __launch_bounds__(256) void bin_and_refine(
    const int* __restrict__ rows, const int* __restrict__ cols,
    int* __restrict__ gcur, u32* __restrict__ tmp, int E, int NB, int bin_blocks,
    const float* __restrict__ pose,
    const u16* __restrict__ wph, const u16* __restrict__ wpl,
    const float* __restrict__ b_pos,
    const u16* __restrict__ wfh, const u16* __restrict__ wfl,
    const float* __restrict__ b_fc,
    u16* __restrict__ y, int n)
{
  __shared__ __align__(16) char smem[34816];
  const int t = threadIdx.x;

  if ((int)blockIdx.x < bin_blocks) {
    int* hist    = (int*)smem;
    int* scanbuf = (int*)(smem + 1024);
    int* lstart  = (int*)(smem + 2048);
    int* lcur    = (int*)(smem + 3072);
    int* gbase   = (int*)(smem + 4096);
    u32* stage   = (u32*)(smem + 5120);
    u8*  sbuck   = (u8*)(smem + 5120 + 16384);
    const int e0 = blockIdx.x * 4096;
    const int cnt = min(4096, E - e0);

    hist[t] = 0;
    __syncthreads();

    int ec[16], er[16];
    int m = 0;
    for (int i = t; i < cnt; i += 256) {
      int c = cols[e0 + i], r = rows[e0 + i];
      ec[m] = c; er[m] = r; ++m;
      atomicAdd(&hist[c >> 9], 1);
    }
    __syncthreads();

    int v = hist[t];
    scanbuf[t] = v;
    __syncthreads();
    for (int d = 1; d < 256; d <<= 1) {
      int u = (t >= d) ? scanbuf[t - d] : 0;
      __syncthreads();
      scanbuf[t] += u;
      __syncthreads();
    }
    lstart[t] = scanbuf[t] - v;
    lcur[t] = 0;
    __syncthreads();

    for (int k = 0; k < m; ++k) {
      int b = ec[k] >> 9;
      int p = lstart[b] + atomicAdd(&lcur[b], 1);
      stage[p] = ((u32)(ec[k] & 511) << 17) | (u32)er[k];
      sbuck[p] = (u8)b;
    }
    __syncthreads();

    if (t < NB && hist[t] > 0) {
      gbase[t] = t * SLOT + atomicAdd(&gcur[t], hist[t]);
    }
    __syncthreads();

    for (int i = t; i < cnt; i += 256) {
      int b = sbuck[i];
      tmp[gbase[b] + (i - lstart[b])] = stage[i];
    }
  } else {
    u16* x1s  = (u16*)smem;
    u16* wbuf = (u16*)(smem + 17408);
    short8* wb = (short8*)wbuf;
    const int bid = (int)blockIdx.x - bin_blocks;
    const int w = t >> 6;
    const int lane = t & 63;
    const int row_base = bid * 64 + w * 16;
    const int colb = lane & 15;
    const int rsub = (lane >> 4) * 4;
    const int asub = (lane >> 4) * 8;

    {
      const int arow_raw = row_base + (lane & 15);
      const int arow = (arow_raw < n) ? arow_raw : 0;
      const float* xrow = pose + (size_t)arow * 64 + asub;
      short8 ap[2];
      #pragma unroll
      for (int ks = 0; ks < 2; ++ks) {
        float4 v0 = *(const float4*)(xrow + ks * 32);
        float4 v1 = *(const float4*)(xrow + ks * 32 + 4);
        float xv[8] = {v0.x, v0.y, v0.z, v0.w, v1.x, v1.y, v1.z, v1.w};
        #pragma unroll
        for (int b = 0; b < 8; ++b) ap[ks][b] = (short)f2bf(xv[b]);
      }
      f32x4 acc[8];
      #pragma unroll
      for (int ct = 0; ct < 8; ++ct) acc[ct] = (f32x4){0.f, 0.f, 0.f, 0.f};
      const short8* WH = (const short8*)wph;
      const short8* WL = (const short8*)wpl;
      #pragma unroll
      for (int ks = 0; ks < 2; ++ks) {
        __syncthreads();
        #pragma unroll
        for (int j = t; j < 1024; j += 256) {
          int ct = j >> 7;
          int hl = (j >> 6) & 1;
          int ls = j & 63;
          wb[j] = (hl ? WL : WH)[(ct * 2 + ks) * 64 + ls];
        }
        __syncthreads();
        #pragma unroll
        for (int ct = 0; ct < 8; ++ct) {
          short8 bh = wb[ct * 128 + lane];
          short8 bl = wb[ct * 128 + 64 + lane];
          acc[ct] = __builtin_amdgcn_mfma_f32_16x16x32_bf16(ap[ks], bh, acc[ct], 0, 0, 0);
          acc[ct] = __builtin_amdgcn_mfma_f32_16x16x32_bf16(ap[ks], bl, acc[ct], 0, 0, 0);
        }
      }
      #pragma unroll
      for (int ct = 0; ct < 8; ++ct) {
        float bb = b_pos[ct * 16 + colb];
        #pragma unroll
        for (int r = 0; r < 4; ++r)
          x1s[(w * 16 + rsub + r) * 136 + ct * 16 + colb] = f2bf(lrelu(acc[ct][r] + bb));
      }
    }
    __syncthreads();

    {
      f32x4 acc[8];
      #pragma unroll
      for (int ct = 0; ct < 8; ++ct) acc[ct] = (f32x4){0.f, 0.f, 0.f, 0.f};
      const short8* WH = (const short8*)wfh;
      const short8* WL = (const short8*)wfl;
      const u16* x1row = x1s + (w * 16 + (lane & 15)) * 136;
      #pragma unroll
      for (int ks = 0; ks < 4; ++ks) {
        __syncthreads();
        #pragma unroll
        for (int j = t; j < 1024; j += 256) {
          int ct = j >> 7;
          int hl = (j >> 6) & 1;
          int ls = j & 63;
          wb[j] = (hl ? WL : WH)[(ct * 4 + ks) * 64 + ls];
        }
        __syncthreads();
        short8 ah = *(const short8*)(x1row + ks * 32 + asub);
        #pragma unroll
        for (int ct = 0; ct < 8; ++ct) {
          short8 bh = wb[ct * 128 + lane];
          short8 bl = wb[ct * 128 + 64 + lane];
          acc[ct] = __builtin_amdgcn_mfma_f32_16x16x32_bf16(ah, bh, acc[ct], 0, 0, 0);
          acc[ct] = __builtin_amdgcn_mfma_f32_16x16x32_bf16(ah, bl, acc[ct], 0, 0, 0);
        }
      }
      #pragma unroll
      for (int r = 0; r < 4; ++r) {
        int row = row_base + rsub + r;
        if (row >= n) continue;
        #pragma unroll
        for (int ct = 0; ct < 8; ++ct)
          y[(size_t)row * 128 + ct * 16 + colb] = f2bf(acc[ct][r] + b_fc[ct * 16 + colb]);
      }
    }
  }
}

// ---------------- CSR pass B ----------------
__global__ __launch_bounds__(256) void bucket_csr(const u32* __restrict__ tmp,
                                                  const int* __restrict__ gcur,
                                                  int* __restrict__ off,
                                                  int* __restrict__ deg,
                                                  float* __restrict__ dis,
                                                  int* __restrict__ csr, int n) {
  const int b = blockIdx.x;
  const int c0 = b << 9;
  const int ncols = min(512, n - c0);
  const int base = b * SLOT;
  const int bcnt = gcur[b];
  __shared__ int hist[512];
  __shared__ int scanbuf[256];
  __shared__ int lofs[512];
  __shared__ int lcur[512];
  __shared__ int img[12288];
  const int t = threadIdx.x;

  for (int i = t; i < 512; i += 256) { hist[i] = 0; lcur[i] = 0; }
  __syncthreads();
  for (int i = t; i < bcnt; i += 256) {
    atomicAdd(&hist[tmp[base + i] >> 17], 1);
  }
  __syncthreads();

  int a0 = hist[2 * t], a1 = hist[2 * t + 1];
  int v = a0 + a1;
  scanbuf[t] = v;
  __syncthreads();
  for (int d = 1; d < 256; d <<= 1) {
    int u = (t >= d) ? scanbuf[t - d] : 0;
    __syncthreads();
    scanbuf[t] += u;
    __syncthreads();
  }
  int ex = scanbuf[t] - v;
  lofs[2 * t] = ex;
  lofs[2 * t + 1] = ex + a0;
  __syncthreads();

  for (int i = t; i < ncols; i += 256) {
    off[c0 + i] = base + lofs[i];
    deg[c0 + i] = hist[i];
    dis[c0 + i] = rsqrtf((float)hist[i] + 1.0f);
  }

  if (bcnt <= 12288) {
    for (int i = t; i < bcnt; i += 256) {
      u32 p = tmp[base + i];
      int lc = p >> 17;
      int pos = atomicAdd(&lcur[lc], 1);
      img[lofs[lc] + pos] = (int)(p & 0x1FFFFu);
    }
    __syncthreads();
    for (int i = t; i < bcnt; i += 256) csr[base + i] = img[i];
  } else {
    for (int i = t; i < bcnt; i += 256) {
      u32 p = tmp[base + i];
      int lc = p >> 17;
      int pos = atomicAdd(&lcur[lc], 1);
      csr[base + lofs[lc] + pos] = (int)(p & 0x1FFFFu);
    }
  }
}

// ---- conv1 GEMM: bf16 in -> fp8 out; W staged through LDS ----
template<int K, int C>
__global__ __launch_bounds__(256) void gemm_conv(
    const u16* __restrict__ x,
    const u16* __restrict__ whi, const u16* __restrict__ wlo,
    const float* __restrict__ rowscale, u8* __restrict__ y, int n)
{
  constexpr int NC = C / 16;
  constexpr int KS = K / 32;
  constexpr int CH = NC * 2 * 64;
  __shared__ __align__(16) u16 wbuf[CH * 8];
  const int t = threadIdx.x;
  const int w = t >> 6;
  const int lane = t & 63;
  const int row_base = blockIdx.x * 128 + w * 32;
  const int a0r = row_base + (lane & 15);
  const int a1r = a0r + 16;
  const int arow0 = (a0r < n) ? a0r : 0;
  const int arow1 = (a1r < n) ? a1r : 0;
  const int asub = (lane >> 4) * 8;
  const u16* xrow0 = x + (size_t)arow0 * K + asub;
  const u16* xrow1 = x + (size_t)arow1 * K + asub;

  short8 a0[KS], a1[KS];
  #pragma unroll
  for (int ks = 0; ks < KS; ++ks) {
    a0[ks] = *(const short8*)(xrow0 + ks * 32);
    a1[ks] = *(const short8*)(xrow1 + ks * 32);
  }

  f32x4 acc[2][NC];
  #pragma unroll
  for (int f = 0; f < 2; ++f)
    #pragma unroll
    for (int ct = 0; ct < NC; ++ct) acc[f][ct] = (f32x4){0.f, 0.f, 0.f, 0.f};

  const short8* WH = (const short8*)whi;
  const short8* WL = (const short8*)wlo;
  short8* wb = (short8*)wbuf;

  #pragma unroll
  for (int ks = 0; ks < KS; ++ks) {
    __syncthreads();
    #pragma unroll
    for (int j = t; j < CH; j += 256) {
      int ct = j >> 7;
      int hl = (j >> 6) & 1;
      int ls = j & 63;
      wb[j] = (hl ? WL : WH)[(ct * KS + ks) * 64 + ls];
    }
    __syncthreads();
    #pragma unroll
    for (int ct = 0; ct < NC; ++ct) {
      short8 bh = wb[ct * 128 + lane];
      short8 bl = wb[ct * 128 + 64 + lane];
      acc[0][ct] = __builtin_amdgcn_mfma_f32_16x16x32_bf16(a0[ks], bh, acc[0][ct], 0, 0, 0);
      acc[1][ct] = __builtin_amdgcn_mfma_f32_16x16x32_bf16(a1[ks], bh, acc[1][ct], 0, 0, 0);
      acc[0][ct] = __builtin_amdgcn_mfma_f32_16x16x32_bf16(a0[ks], bl, acc[0][ct], 0, 0, 0);
      acc[1][ct] = __builtin_amdgcn_mfma_f32_16x16x32_bf16(a1[ks], bl, acc[1][ct], 0, 0, 0);
    }
  }

  const int colb = lane & 15;
  const int rsub = (lane >> 4) * 4;
  #pragma unroll
  for (int f = 0; f < 2; ++f)
    #pragma unroll
    for (int r = 0; r < 4; ++r) {
      int row = row_base + f * 16 + rsub + r;
      if (row >= n) continue;
      float sc = rowscale[row] * F8SCALE;
      #pragma unroll
      for (int ct = 0; ct < NC; ++ct)
        y[(size_t)row * C + ct * 16 + colb] = f2f8(acc[f][ct][r] * sc);
    }
}

// ---------------- fp8 gather bursts ----------------
template<int U>
__device__ __forceinline__ void gulpf8_128(const u8* __restrict__ hs, int idx, int j,
                                           u32 loff, f32x2* acc) {
  uint2 a[U];
  #pragma unroll
  for (int u = 0; u < U; ++u) {
    u32 r = (u32)__shfl(idx, j + u, 16);
    a[u] = *(const uint2*)(hs + (r << 7) + loff);
  }
  #pragma unroll
  for (int u = 0; u < U; ++u) {
    accf8p(acc, a[u].x);
    accf8p(acc + 2, a[u].y);
  }
}

template<int U>
__device__ __forceinline__ void gulpf8_64(const u8* __restrict__ hs, int idx, int j,
                                          u32 loff, f32x2* acc) {
  u32 a[U];
  #pragma unroll
  for (int u = 0; u < U; ++u) {
    u32 r = (u32)__shfl(idx, j + u, 16);
    a[u] = *(const u32*)(hs + (r << 6) + loff);
  }
  #pragma unroll
  for (int u = 0; u < U; ++u) accf8p(acc, a[u]);
}

// ---- FUSED gather + conv: gather 128 nodes -> LDS bf16 tile -> GEMM -> fp8 out ----
// hs: prev conv out (fp8, 128 cols). bias: prev conv bias. whi/wlo: next weights.
template<int CO>
__global__ __launch_bounds__(256) void gather_conv(
    const int* __restrict__ csr, const int* __restrict__ off, const int* __restrict__ deg,
    const u8* __restrict__ hs, const float* __restrict__ dis,
    const float* __restrict__ bias,
    const u16* __restrict__ whi, const u16* __restrict__ wlo,
    u8* __restrict__ y, int n)
{
  constexpr int NC = CO / 16;
  constexpr int CH = NC * 2 * 64;     // short8 per ks chunk
  __shared__ __align__(16) u16 xt[128 * 136];   // 34816 B bf16 tile
  __shared__ __align__(16) u16 wbuf[CH * 8];
  const int t = threadIdx.x;
  const int nb = blockIdx.x * 128;

  // ---- phase 1: gather 128 nodes (16 lanes/node, 8 groups) ----
  {
    const int l = t & 15;
    const u32 loff = (u32)l << 3;
    #pragma unroll
    for (int g = 0; g < 8; ++g) {
      const int nl = g * 16 + (t >> 4);
      const int node = nb + nl;
      if (node < n) {
        const int o = off[node];
        const int d = deg[node];
        const float dd = dis[node] * F8INV;
        f32x2 acc[4];
        {
          uint2 hv = *(const uint2*)(hs + ((u32)node << 7) + loff);
          setf8p(acc, hv.x);
          setf8p(acc + 2, hv.y);
        }
        for (int base = 0; base < d; base += 16) {
          const int batch = min(d - base, 16);
          int idx = (l < batch) ? csr[o + base + l] : 0;
          int j = 0;
          for (; j + 8 <= batch; j += 8) gulpf8_128<8>(hs, idx, j, loff, acc);
          if (j + 4 <= batch) { gulpf8_128<4>(hs, idx, j, loff, acc); j += 4; }
          for (; j < batch; ++j) gulpf8_128<1>(hs, idx, j, loff, acc);
        }
        float4 b0 = *(const float4*)(bias + l * 8);
        float4 b1 = *(const float4*)(bias + l * 8 + 4);
        float o0 = lrelu(acc[0][0] * dd + b0.x), o1 = lrelu(acc[0][1] * dd + b0.y);
        float o2 = lrelu(acc[1][0] * dd + b0.z), o3 = lrelu(acc[1][1] * dd + b0.w);
        float o4 = lrelu(acc[2][0] * dd + b1.x), o5 = lrelu(acc[2][1] * dd + b1.y);
        float o6 = lrelu(acc[3][0] * dd + b1.z), o7 = lrelu(acc[3][1] * dd + b1.w);
        uint4 wv;
        wv.x = ((u32)f2bf(o1) << 16) | f2bf(o0);
        wv.y = ((u32)f2bf(o3) << 16) | f2bf(o2);
        wv.z = ((u32)f2bf(o5) << 16) | f2bf(o4);
        wv.w = ((u32)f2bf(o7) << 16) | f2bf(o6);
        *(uint4*)&xt[nl * 136 + l * 8] = wv;
      }
    }
  }
  __syncthreads();

  // ---- phase 2: conv GEMM (A from LDS) ----
  {
    const int w = t >> 6;
    const int lane = t & 63;
    const int asub = (lane >> 4) * 8;
    const int rl0 = w * 32 + (lane & 15);
    const int rl1 = rl0 + 16;

    short8 a0[4], a1[4];
    #pragma unroll
    for (int ks = 0; ks < 4; ++ks) {
      a0[ks] = *(const short8*)&xt[rl0 * 136 + ks * 32 + asub];
      a1[ks] = *(const short8*)&xt[rl1 * 136 + ks * 32 + asub];
    }

    f32x4 acc[2][NC];
    #pragma unroll
    for (int f = 0; f < 2; ++f)
      #pragma unroll
      for (int ct = 0; ct < NC; ++ct) acc[f][ct] = (f32x4){0.f, 0.f, 0.f, 0.f};

    const short8* WH = (const short8*)whi;
    const short8* WL = (const short8*)wlo;
    short8* wb = (short8*)wbuf;

    #pragma unroll
    for (int ks = 0; ks < 4; ++ks) {
      __syncthreads();
      #pragma unroll
      for (int j = t; j < CH; j += 256) {
        int ct = j >> 7;
        int hl = (j >> 6) & 1;
        int ls = j & 63;
        wb[j] = (hl ? WL : WH)[(ct * 4 + ks) * 64 + ls];
      }
      __syncthreads();
      #pragma unroll
      for (int ct = 0; ct < NC; ++ct) {
        short8 bh = wb[ct * 128 + lane];
        short8 bl = wb[ct * 128 + 64 + lane];
        acc[0][ct] = __builtin_amdgcn_mfma_f32_16x16x32_bf16(a0[ks], bh, acc[0][ct], 0, 0, 0);
        acc[1][ct] = __builtin_amdgcn_mfma_f32_16x16x32_bf16(a1[ks], bh, acc[1][ct], 0, 0, 0);
        acc[0][ct] = __builtin_amdgcn_mfma_f32_16x16x32_bf16(a0[ks], bl, acc[0][ct], 0, 0, 0);
        acc[1][ct] = __builtin_amdgcn_mfma_f32_16x16x32_bf16(a1[ks], bl, acc[1][ct], 0, 0, 0);
      }
    }

    const int colb = lane & 15;
    const int rsub = (lane >> 4) * 4;
    #pragma unroll
    for (int f = 0; f < 2; ++f)
      #pragma unroll
      for (int r = 0; r < 4; ++r) {
        int row = nb + w * 32 + f * 16 + rsub + r;
        if (row >= n) continue;
        float sc = dis[row] * F8SCALE;
        #pragma unroll
        for (int ct = 0; ct < NC; ++ct)
          y[(size_t)row * CO + ct * 16 + colb] = f2f8(acc[f][ct][r] * sc);
      }
  }
}

// ---- conv3 output: gather (C=64 fp8) + finalize + block partial sums ----
__global__ __launch_bounds__(256) void gather_mean_part(
    const int* __restrict__ csr, const int* __restrict__ off, const int* __restrict__ deg,
    const u8* __restrict__ hs, const float* __restrict__ dis,
    const float* __restrict__ bias, float* __restrict__ partial, int n)
{
  const int t = threadIdx.x;
  const int l = t & 15;
  const int node = blockIdx.x * 16 + (t >> 4);
  float4 b4 = *(const float4*)(bias + l * 4);
  float4 val = make_float4(0.f, 0.f, 0.f, 0.f);

  if (node < n) {
    const int o = off[node];
    const int d = deg[node];
    const float dd = dis[node] * F8INV;
    const u32 loff = (u32)l << 2;
    f32x2 acc[2];
    setf8p(acc, *(const u32*)(hs + ((u32)node << 6) + loff));
    for (int base = 0; base < d; base += 16) {
      const int batch = min(d - base, 16);
      int idx = (l < batch) ? csr[o + base + l] : 0;
      int j = 0;
      for (; j + 8 <= batch; j += 8) gulpf8_64<8>(hs, idx, j, loff, acc);
      if (j + 4 <= batch) { gulpf8_64<4>(hs, idx, j, loff, acc); j += 4; }
      for (; j < batch; ++j) gulpf8_64<1>(hs, idx, j, loff, acc);
    }
    val.x = lrelu(acc[0][0] * dd + b4.x);
    val.y = lrelu(acc[0][1] * dd + b4.y);
    val.z = lrelu(acc[1][0] * dd + b4.z);
    val.w = lrelu(acc[1][1] * dd + b4.w);
  }

  __shared__ float4 s[256];
  s[t] = val;
  __syncthreads();
  for (int offst = 128; offst >= 16; offst >>= 1) {
    if (t < offst) {
      s[t].x += s[t + offst].x; s[t].y += s[t + offst].y;
      s[t].z += s[t + offst].z; s[t].w += s[t + offst].w;
    }
    __syncthreads();
  }
  if (t < 16) {
    float* slot = partial + (size_t)(blockIdx.x & 31) * 64;
    atomicAdd(slot + t * 4 + 0, s[t].x);
    atomicAdd(slot + t * 4 + 1, s[t].y);
    atomicAdd(slot + t * 4 + 2, s[t].z);
    atomicAdd(slot + t * 4 + 3, s[t].w);
  }
}

__global__ __launch_bounds__(64) void mean_finish(const float* __restrict__ partial,
                                                  float* __restrict__ out, int n) {
  const int c = threadIdx.x;
  float s = 0.f;
  #pragma unroll
  for (int k = 0; k < 32; ++k) s += partial[k * 64 + c];
  out[c] = s / (float)n;
}

extern "C" void kernel_launch(void* const* d_in, const int* in_sizes, int n_in,
                              void* d_out, int out_size, void* d_ws, size_t ws_size,
                              hipStream_t stream) {
  const float* pose = (const float*)d_in[0];
  const float* w_pos = (const float*)d_in[1];
  const float* b_pos = (const float*)d_in[2];
  const float* w_fc  = (const float*)d_in[3];
  const float* b_fc  = (const float*)d_in[4];
  const float* w_g1  = (const float*)d_in[5];
  const float* b_g1  = (const float*)d_in[6];
  const float* w_g2  = (const float*)d_in[7];
  const float* b_g2  = (const float*)d_in[8];
  const float* w_g3  = (const float*)d_in[9];
  const float* b_g3  = (const float*)d_in[10];
  const int*   edges = (const int*)d_in[11];

  const int n = in_sizes[0] / 64;
  const int E = in_sizes[11] / 2;
  const int* rows = edges;
  const int* cols = edges + E;
  const int NB = (n + 511) >> 9;

  char* p = (char*)d_ws;
  auto alloc = [&](size_t bytes) { char* q = p; p += (bytes + 255) & ~(size_t)255; return q; };
  int*   off     = (int*)  alloc((size_t)n * 4);
  int*   deg     = (int*)  alloc((size_t)n * 4);
  int*   misc    = (int*)  alloc((256 + 2048) * 4);
  int*   gcur    = misc;
  float* partial = (float*)(misc + 256);
  float* dis     = (float*)alloc((size_t)n * 4);
  u16* wp_pos_h = (u16*)alloc(1024 * 16);
  u16* wp_pos_l = (u16*)alloc(1024 * 16);
  u16* wp_fc_h  = (u16*)alloc(2048 * 16);
  u16* wp_fc_l  = (u16*)alloc(2048 * 16);
  u16* wp_g1_h  = (u16*)alloc(2048 * 16);
  u16* wp_g1_l  = (u16*)alloc(2048 * 16);
  u16* wp_g2_h  = (u16*)alloc(2048 * 16);
  u16* wp_g2_l  = (u16*)alloc(2048 * 16);
  u16* wp_g3_h  = (u16*)alloc(1024 * 16);
  u16* wp_g3_l  = (u16*)alloc(1024 * 16);
  int*   csr     = (int*)  alloc((size_t)NB * SLOT * 4);
  size_t bufA_sz = (size_t)NB * SLOT * 4;
  size_t act_sz  = (size_t)n * 128;
  if (act_sz > bufA_sz) bufA_sz = act_sz;
  u8*    bufA    = (u8*)   alloc(bufA_sz);            // fp8 hs A / aliases tmp
  u8*    bufC    = (u8*)   alloc((size_t)n * 128);    // fp8 hs B
  u16*   bufB    = (u16*)  alloc((size_t)n * 128 * 2);// bf16 refine output
  u32*   tmp     = (u32*)bufA;

  const int eb4k         = (E + 4095) / 4096;
  const int ref_blocks   = (n + 63) / 64;
  const int conv_blocks  = (n + 127) / 128;
  const int gc_blocks    = (n + 127) / 128;
  const int g_blocks     = (n + 15) / 16;

  // ---- 1: weight packs + misc zeroing ----
  pack_all<<<32, 256, 0, stream>>>(w_pos, w_fc, w_g1, w_g2, w_g3,
      wp_pos_h, wp_pos_l, wp_fc_h, wp_fc_l, wp_g1_h, wp_g1_l,
      wp_g2_h, wp_g2_l, wp_g3_h, wp_g3_l, misc);

  // ---- 2: MERGED bin_pass || refine_fused ----
  bin_and_refine<<<eb4k + ref_blocks, 256, 0, stream>>>(
      rows, cols, gcur, tmp, E, NB, eb4k,
      pose, wp_pos_h, wp_pos_l, b_pos, wp_fc_h, wp_fc_l, b_fc, bufB, n);

  // ---- 3: CSR pass B ----
  bucket_csr<<<NB, 256, 0, stream>>>(tmp, gcur, off, deg, dis, csr, n);

  // ---- 4: conv1 (bufB bf16 -> bufA fp8) ----
  gemm_conv<128, 128><<<conv_blocks, 256, 0, stream>>>(bufB, wp_g1_h, wp_g1_l, dis, bufA, n);

  // ---- 5: fused gather1+conv2 (bufA -> bufC) ----
  gather_conv<128><<<gc_blocks, 256, 0, stream>>>(
      csr, off, deg, bufA, dis, b_g1, wp_g2_h, wp_g2_l, bufC, n);

  // ---- 6: fused gather2+conv3 (bufC -> bufA) ----
  gather_conv<64><<<gc_blocks, 256, 0, stream>>>(
      csr, off, deg, bufC, dis, b_g2, wp_g3_h, wp_g3_l, bufA, n);

  // ---- 7: gather3 + mean ----
  gather_mean_part<<<g_blocks, 256, 0, stream>>>(csr, off, deg, bufA, dis, b_g3, partial, n);
  mean_finish<<<1, 64, 0, stream>>>(partial, (float*)d_out, n);
}

// Round 22
// 229.289 us; speedup vs baseline: 1.3619x; 1.3619x over previous
//
#include <hip/hip_runtime.h>

#define SLOPE 0.01f
#define SLOT  14336

typedef __attribute__((ext_vector_type(8))) short short8;
typedef __attribute__((ext_vector_type(4))) float f32x4;
typedef __attribute__((ext_vector_type(2))) float f32x2;
typedef unsigned short u16;
typedef unsigned int u32;
typedef unsigned char u8;

#define F8SCALE 16.0f
#define F8INV   0.0625f

__device__ __forceinline__ float lrelu(float v) { return v >= 0.0f ? v : SLOPE * v; }

__device__ __forceinline__ u16 f2bf(float f) {
  u32 u = __float_as_uint(f);
  return (u16)((u + 0x7FFF + ((u >> 16) & 1)) >> 16);
}
__device__ __forceinline__ float bf2f(u16 h) {
  return __uint_as_float(((u32)h) << 16);
}
__device__ __forceinline__ u8 f2f8(float v) {
  return (u8)__builtin_amdgcn_cvt_pk_fp8_f32(v, v, 0, false);
}
__device__ __forceinline__ void accf8p(f32x2* acc, u32 w) {
  acc[0] += __builtin_amdgcn_cvt_pk_f32_fp8(w, false);
  acc[1] += __builtin_amdgcn_cvt_pk_f32_fp8(w, true);
}
__device__ __forceinline__ void setf8p(f32x2* acc, u32 w) {
  acc[0] = __builtin_amdgcn_cvt_pk_f32_fp8(w, false);
  acc[1] = __builtin_amdgcn_cvt_pk_f32_fp8(w, true);
}

// ---- one-shot W pack (all 5 weights) + zero misc ----
__global__ __launch_bounds__(256) void pack_all(
    const float* __restrict__ W0, const float* __restrict__ W1, const float* __restrict__ W2,
    const float* __restrict__ W3, const float* __restrict__ W4,
    u16* __restrict__ H0, u16* __restrict__ L0, u16* __restrict__ H1, u16* __restrict__ L1,
    u16* __restrict__ H2, u16* __restrict__ L2, u16* __restrict__ H3, u16* __restrict__ L3,
    u16* __restrict__ H4, u16* __restrict__ L4, int* __restrict__ misc)
{
  const int g = blockIdx.x * 256 + threadIdx.x;
  if (g < 2304) misc[g] = 0;    // gcur(256) + partial(2048)
  int t = g;
  const float* W; u16* hi; u16* lo; int K, C;
  if (t < 1024)      { W = W0; hi = H0; lo = L0; K = 64;  C = 128; }
  else if (t < 3072) { W = W1; hi = H1; lo = L1; K = 128; C = 128; t -= 1024; }
  else if (t < 5120) { W = W2; hi = H2; lo = L2; K = 128; C = 128; t -= 3072; }
  else if (t < 7168) { W = W3; hi = H3; lo = L3; K = 128; C = 128; t -= 5120; }
  else               { W = W4; hi = H4; lo = L4; K = 128; C = 64;  t -= 7168; }
  const int KS = K / 32;
  int l = t & 63;
  int rest = t >> 6;
  int ks = rest % KS;
  int ct = rest / KS;
  int k0 = ks * 32 + (l >> 4) * 8;
  int c  = ct * 16 + (l & 15);
  short8 hv, lv;
  #pragma unroll
  for (int b = 0; b < 8; ++b) {
    float v = W[(size_t)(k0 + b) * C + c];
    u16 h = f2bf(v);
    hv[b] = (short)h;
    lv[b] = (short)f2bf(v - bf2f(h));
  }
  ((short8*)hi)[t] = hv;
  ((short8*)lo)[t] = lv;
}

// ---- MERGED: bin_pass (blocks < bin_blocks) || refine_fused (rest) ----
__global__ __launch_bounds__(256) void bin_and_refine(
    const int* __restrict__ rows, const int* __restrict__ cols,
    int* __restrict__ gcur, u32* __restrict__ tmp, int E, int NB, int bin_blocks,
    const float* __restrict__ pose,
    const u16* __restrict__ wph, const u16* __restrict__ wpl,
    const float* __restrict__ b_pos,
    const u16* __restrict__ wfh, const u16* __restrict__ wfl,
    const float* __restrict__ b_fc,
    u16* __restrict__ y, int n)
{
  __shared__ __align__(16) char smem[34816];
  const int t = threadIdx.x;

  if ((int)blockIdx.x < bin_blocks) {
    int* hist    = (int*)smem;
    int* scanbuf = (int*)(smem + 1024);
    int* lstart  = (int*)(smem + 2048);
    int* lcur    = (int*)(smem + 3072);
    int* gbase   = (int*)(smem + 4096);
    u32* stage   = (u32*)(smem + 5120);
    u8*  sbuck   = (u8*)(smem + 5120 + 16384);
    const int e0 = blockIdx.x * 4096;
    const int cnt = min(4096, E - e0);

    hist[t] = 0;
    __syncthreads();

    int ec[16], er[16];
    int m = 0;
    for (int i = t; i < cnt; i += 256) {
      int c = cols[e0 + i], r = rows[e0 + i];
      ec[m] = c; er[m] = r; ++m;
      atomicAdd(&hist[c >> 9], 1);
    }
    __syncthreads();

    int v = hist[t];
    scanbuf[t] = v;
    __syncthreads();
    for (int d = 1; d < 256; d <<= 1) {
      int u = (t >= d) ? scanbuf[t - d] : 0;
      __syncthreads();
      scanbuf[t] += u;
      __syncthreads();
    }
    lstart[t] = scanbuf[t] - v;
    lcur[t] = 0;
    __syncthreads();

    for (int k = 0; k < m; ++k) {
      int b = ec[k] >> 9;
      int p = lstart[b] + atomicAdd(&lcur[b], 1);
      stage[p] = ((u32)(ec[k] & 511) << 17) | (u32)er[k];
      sbuck[p] = (u8)b;
    }
    __syncthreads();

    if (t < NB && hist[t] > 0) {
      gbase[t] = t * SLOT + atomicAdd(&gcur[t], hist[t]);
    }
    __syncthreads();

    for (int i = t; i < cnt; i += 256) {
      int b = sbuck[i];
      tmp[gbase[b] + (i - lstart[b])] = stage[i];
    }
  } else {
    u16* x1s  = (u16*)smem;                 // [4][16][136] flattened
    u16* wbuf = (u16*)(smem + 17408);
    short8* wb = (short8*)wbuf;
    const int bid = (int)blockIdx.x - bin_blocks;
    const int w = t >> 6;
    const int lane = t & 63;
    const int row_base = bid * 64 + w * 16;
    const int colb = lane & 15;
    const int rsub = (lane >> 4) * 4;
    const int asub = (lane >> 4) * 8;

    {
      const int arow_raw = row_base + (lane & 15);
      const int arow = (arow_raw < n) ? arow_raw : 0;
      const float* xrow = pose + (size_t)arow * 64 + asub;
      short8 ap[2];
      #pragma unroll
      for (int ks = 0; ks < 2; ++ks) {
        float4 v0 = *(const float4*)(xrow + ks * 32);
        float4 v1 = *(const float4*)(xrow + ks * 32 + 4);
        float xv[8] = {v0.x, v0.y, v0.z, v0.w, v1.x, v1.y, v1.z, v1.w};
        #pragma unroll
        for (int b = 0; b < 8; ++b) ap[ks][b] = (short)f2bf(xv[b]);
      }
      f32x4 acc[8];
      #pragma unroll
      for (int ct = 0; ct < 8; ++ct) acc[ct] = (f32x4){0.f, 0.f, 0.f, 0.f};
      const short8* WH = (const short8*)wph;
      const short8* WL = (const short8*)wpl;
      #pragma unroll
      for (int ks = 0; ks < 2; ++ks) {
        __syncthreads();
        #pragma unroll
        for (int j = t; j < 1024; j += 256) {
          int ct = j >> 7;
          int hl = (j >> 6) & 1;
          int ls = j & 63;
          wb[j] = (hl ? WL : WH)[(ct * 2 + ks) * 64 + ls];
        }
        __syncthreads();
        #pragma unroll
        for (int ct = 0; ct < 8; ++ct) {
          short8 bh = wb[ct * 128 + lane];
          short8 bl = wb[ct * 128 + 64 + lane];
          acc[ct] = __builtin_amdgcn_mfma_f32_16x16x32_bf16(ap[ks], bh, acc[ct], 0, 0, 0);
          acc[ct] = __builtin_amdgcn_mfma_f32_16x16x32_bf16(ap[ks], bl, acc[ct], 0, 0, 0);
        }
      }
      #pragma unroll
      for (int ct = 0; ct < 8; ++ct) {
        float bb = b_pos[ct * 16 + colb];
        #pragma unroll
        for (int r = 0; r < 4; ++r)
          x1s[(w * 16 + rsub + r) * 136 + ct * 16 + colb] = f2bf(lrelu(acc[ct][r] + bb));
      }
    }
    __syncthreads();

    {
      f32x4 acc[8];
      #pragma unroll
      for (int ct = 0; ct < 8; ++ct) acc[ct] = (f32x4){0.f, 0.f, 0.f, 0.f};
      const short8* WH = (const short8*)wfh;
      const short8* WL = (const short8*)wfl;
      const u16* x1row = x1s + (w * 16 + (lane & 15)) * 136;
      #pragma unroll
      for (int ks = 0; ks < 4; ++ks) {
        __syncthreads();
        #pragma unroll
        for (int j = t; j < 1024; j += 256) {
          int ct = j >> 7;
          int hl = (j >> 6) & 1;
          int ls = j & 63;
          wb[j] = (hl ? WL : WH)[(ct * 4 + ks) * 64 + ls];
        }
        __syncthreads();
        short8 ah = *(const short8*)(x1row + ks * 32 + asub);
        #pragma unroll
        for (int ct = 0; ct < 8; ++ct) {
          short8 bh = wb[ct * 128 + lane];
          short8 bl = wb[ct * 128 + 64 + lane];
          acc[ct] = __builtin_amdgcn_mfma_f32_16x16x32_bf16(ah, bh, acc[ct], 0, 0, 0);
          acc[ct] = __builtin_amdgcn_mfma_f32_16x16x32_bf16(ah, bl, acc[ct], 0, 0, 0);
        }
      }
      #pragma unroll
      for (int r = 0; r < 4; ++r) {
        int row = row_base + rsub + r;
        if (row >= n) continue;
        #pragma unroll
        for (int ct = 0; ct < 8; ++ct)
          y[(size_t)row * 128 + ct * 16 + colb] = f2bf(acc[ct][r] + b_fc[ct * 16 + colb]);
      }
    }
  }
}

// ---------------- CSR pass B: per-bucket hist + scan + LDS scatter + flush ----------------
__global__ __launch_bounds__(256) void bucket_csr(const u32* __restrict__ tmp,
                                                  const int* __restrict__ gcur,
                                                  int* __restrict__ off,
                                                  int* __restrict__ deg,
                                                  float* __restrict__ dis,
                                                  int* __restrict__ csr, int n) {
  const int b = blockIdx.x;
  const int c0 = b << 9;
  const int ncols = min(512, n - c0);
  const int base = b * SLOT;
  const int bcnt = gcur[b];
  __shared__ int hist[512];
  __shared__ int scanbuf[256];
  __shared__ int lofs[512];
  __shared__ int lcur[512];
  __shared__ int img[12288];
  const int t = threadIdx.x;

  for (int i = t; i < 512; i += 256) { hist[i] = 0; lcur[i] = 0; }
  __syncthreads();
  for (int i = t; i < bcnt; i += 256) {
    atomicAdd(&hist[tmp[base + i] >> 17], 1);
  }
  __syncthreads();

  int a0 = hist[2 * t], a1 = hist[2 * t + 1];
  int v = a0 + a1;
  scanbuf[t] = v;
  __syncthreads();
  for (int d = 1; d < 256; d <<= 1) {
    int u = (t >= d) ? scanbuf[t - d] : 0;
    __syncthreads();
    scanbuf[t] += u;
    __syncthreads();
  }
  int ex = scanbuf[t] - v;
  lofs[2 * t] = ex;
  lofs[2 * t + 1] = ex + a0;
  __syncthreads();

  for (int i = t; i < ncols; i += 256) {
    off[c0 + i] = base + lofs[i];
    deg[c0 + i] = hist[i];
    dis[c0 + i] = rsqrtf((float)hist[i] + 1.0f);
  }

  if (bcnt <= 12288) {
    for (int i = t; i < bcnt; i += 256) {
      u32 p = tmp[base + i];
      int lc = p >> 17;
      int pos = atomicAdd(&lcur[lc], 1);
      img[lofs[lc] + pos] = (int)(p & 0x1FFFFu);
    }
    __syncthreads();
    for (int i = t; i < bcnt; i += 256) csr[base + i] = img[i];
  } else {  // statistically unreachable fallback
    for (int i = t; i < bcnt; i += 256) {
      u32 p = tmp[base + i];
      int lc = p >> 17;
      int pos = atomicAdd(&lcur[lc], 1);
      csr[base + lofs[lc] + pos] = (int)(p & 0x1FFFFu);
    }
  }
}

// ---- conv GEMM: bf16 in -> fp8 out; W staged through LDS per K-chunk ----
template<int K, int C>
__global__ __launch_bounds__(256) void gemm_conv(
    const u16* __restrict__ x,
    const u16* __restrict__ whi, const u16* __restrict__ wlo,
    const float* __restrict__ rowscale, u8* __restrict__ y, int n)
{
  constexpr int NC = C / 16;
  constexpr int KS = K / 32;
  constexpr int CH = NC * 2 * 64;
  __shared__ __align__(16) u16 wbuf[CH * 8];
  const int t = threadIdx.x;
  const int w = t >> 6;
  const int lane = t & 63;
  const int row_base = blockIdx.x * 128 + w * 32;
  const int a0r = row_base + (lane & 15);
  const int a1r = a0r + 16;
  const int arow0 = (a0r < n) ? a0r : 0;
  const int arow1 = (a1r < n) ? a1r : 0;
  const int asub = (lane >> 4) * 8;
  const u16* xrow0 = x + (size_t)arow0 * K + asub;
  const u16* xrow1 = x + (size_t)arow1 * K + asub;

  short8 a0[KS], a1[KS];
  #pragma unroll
  for (int ks = 0; ks < KS; ++ks) {
    a0[ks] = *(const short8*)(xrow0 + ks * 32);
    a1[ks] = *(const short8*)(xrow1 + ks * 32);
  }

  f32x4 acc[2][NC];
  #pragma unroll
  for (int f = 0; f < 2; ++f)
    #pragma unroll
    for (int ct = 0; ct < NC; ++ct) acc[f][ct] = (f32x4){0.f, 0.f, 0.f, 0.f};

  const short8* WH = (const short8*)whi;
  const short8* WL = (const short8*)wlo;
  short8* wb = (short8*)wbuf;

  #pragma unroll
  for (int ks = 0; ks < KS; ++ks) {
    __syncthreads();
    #pragma unroll
    for (int j = t; j < CH; j += 256) {
      int ct = j >> 7;
      int hl = (j >> 6) & 1;
      int ls = j & 63;
      wb[j] = (hl ? WL : WH)[(ct * KS + ks) * 64 + ls];
    }
    __syncthreads();
    #pragma unroll
    for (int ct = 0; ct < NC; ++ct) {
      short8 bh = wb[ct * 128 + lane];
      short8 bl = wb[ct * 128 + 64 + lane];
      acc[0][ct] = __builtin_amdgcn_mfma_f32_16x16x32_bf16(a0[ks], bh, acc[0][ct], 0, 0, 0);
      acc[1][ct] = __builtin_amdgcn_mfma_f32_16x16x32_bf16(a1[ks], bh, acc[1][ct], 0, 0, 0);
      acc[0][ct] = __builtin_amdgcn_mfma_f32_16x16x32_bf16(a0[ks], bl, acc[0][ct], 0, 0, 0);
      acc[1][ct] = __builtin_amdgcn_mfma_f32_16x16x32_bf16(a1[ks], bl, acc[1][ct], 0, 0, 0);
    }
  }

  const int colb = lane & 15;
  const int rsub = (lane >> 4) * 4;
  #pragma unroll
  for (int f = 0; f < 2; ++f)
    #pragma unroll
    for (int r = 0; r < 4; ++r) {
      int row = row_base + f * 16 + rsub + r;
      if (row >= n) continue;
      float sc = rowscale[row] * F8SCALE;
      #pragma unroll
      for (int ct = 0; ct < NC; ++ct)
        y[(size_t)row * C + ct * 16 + colb] = f2f8(acc[f][ct][r] * sc);
    }
}

// ---------------- fp8 gather bursts (packed cvt + packed adds) ----------------
template<int U>
__device__ __forceinline__ void gulpf8_128(const u8* __restrict__ hs, int idx, int j,
                                           u32 loff, f32x2* acc) {
  uint2 a[U];
  #pragma unroll
  for (int u = 0; u < U; ++u) {
    u32 r = (u32)__shfl(idx, j + u, 16);
    a[u] = *(const uint2*)(hs + (r << 7) + loff);
  }
  #pragma unroll
  for (int u = 0; u < U; ++u) {
    accf8p(acc, a[u].x);
    accf8p(acc + 2, a[u].y);
  }
}

template<int U>
__device__ __forceinline__ void gulpf8_64(const u8* __restrict__ hs, int idx, int j,
                                          u32 loff, f32x2* acc) {
  u32 a[U];
  #pragma unroll
  for (int u = 0; u < U; ++u) {
    u32 r = (u32)__shfl(idx, j + u, 16);
    a[u] = *(const u32*)(hs + (r << 6) + loff);
  }
  #pragma unroll
  for (int u = 0; u < U; ++u) accf8p(acc, a[u]);
}

// ---- gather (C=128, fp8 hs -> bf16 out): 16 lanes/node, 8 cols/lane ----
__global__ __launch_bounds__(256) void gather_f8_128(
    const int* __restrict__ csr, const int* __restrict__ off, const int* __restrict__ deg,
    const u8* __restrict__ hs, const float* __restrict__ dis,
    const float* __restrict__ bias, u16* __restrict__ y, int n)
{
  const int t = threadIdx.x;
  const int l = t & 15;
  const int node = blockIdx.x * 16 + (t >> 4);
  if (node >= n) return;
  const int o = off[node];
  const int d = deg[node];
  const float dd = dis[node] * F8INV;
  const u32 loff = (u32)l << 3;

  f32x2 acc[4];
  {
    uint2 hv = *(const uint2*)(hs + ((u32)node << 7) + loff);
    setf8p(acc, hv.x);
    setf8p(acc + 2, hv.y);
  }

  for (int base = 0; base < d; base += 16) {
    const int batch = min(d - base, 16);
    int idx = (l < batch) ? csr[o + base + l] : 0;
    int j = 0;
    for (; j + 8 <= batch; j += 8) gulpf8_128<8>(hs, idx, j, loff, acc);
    if (j + 4 <= batch) { gulpf8_128<4>(hs, idx, j, loff, acc); j += 4; }
    for (; j < batch; ++j) gulpf8_128<1>(hs, idx, j, loff, acc);
  }

  float4 b0 = *(const float4*)(bias + l * 8);
  float4 b1 = *(const float4*)(bias + l * 8 + 4);
  float o0 = lrelu(acc[0][0] * dd + b0.x), o1 = lrelu(acc[0][1] * dd + b0.y);
  float o2 = lrelu(acc[1][0] * dd + b0.z), o3 = lrelu(acc[1][1] * dd + b0.w);
  float o4 = lrelu(acc[2][0] * dd + b1.x), o5 = lrelu(acc[2][1] * dd + b1.y);
  float o6 = lrelu(acc[3][0] * dd + b1.z), o7 = lrelu(acc[3][1] * dd + b1.w);
  uint4 wv;
  wv.x = ((u32)f2bf(o1) << 16) | f2bf(o0);
  wv.y = ((u32)f2bf(o3) << 16) | f2bf(o2);
  wv.z = ((u32)f2bf(o5) << 16) | f2bf(o4);
  wv.w = ((u32)f2bf(o7) << 16) | f2bf(o6);
  *(uint4*)(y + (size_t)node * 128 + l * 8) = wv;
}

// ---- conv3: gather (C=64 fp8) + finalize + block partial sums ----
__global__ __launch_bounds__(256) void gather_mean_part(
    const int* __restrict__ csr, const int* __restrict__ off, const int* __restrict__ deg,
    const u8* __restrict__ hs, const float* __restrict__ dis,
    const float* __restrict__ bias, float* __restrict__ partial, int n)
{
  const int t = threadIdx.x;
  const int l = t & 15;
  const int node = blockIdx.x * 16 + (t >> 4);
  float4 b4 = *(const float4*)(bias + l * 4);
  float4 val = make_float4(0.f, 0.f, 0.f, 0.f);

  if (node < n) {
    const int o = off[node];
    const int d = deg[node];
    const float dd = dis[node] * F8INV;
    const u32 loff = (u32)l << 2;
    f32x2 acc[2];
    setf8p(acc, *(const u32*)(hs + ((u32)node << 6) + loff));
    for (int base = 0; base < d; base += 16) {
      const int batch = min(d - base, 16);
      int idx = (l < batch) ? csr[o + base + l] : 0;
      int j = 0;
      for (; j + 8 <= batch; j += 8) gulpf8_64<8>(hs, idx, j, loff, acc);
      if (j + 4 <= batch) { gulpf8_64<4>(hs, idx, j, loff, acc); j += 4; }
      for (; j < batch; ++j) gulpf8_64<1>(hs, idx, j, loff, acc);
    }
    val.x = lrelu(acc[0][0] * dd + b4.x);
    val.y = lrelu(acc[0][1] * dd + b4.y);
    val.z = lrelu(acc[1][0] * dd + b4.z);
    val.w = lrelu(acc[1][1] * dd + b4.w);
  }

  __shared__ float4 s[256];
  s[t] = val;
  __syncthreads();
  for (int offst = 128; offst >= 16; offst >>= 1) {
    if (t < offst) {
      s[t].x += s[t + offst].x; s[t].y += s[t + offst].y;
      s[t].z += s[t + offst].z; s[t].w += s[t + offst].w;
    }
    __syncthreads();
  }
  if (t < 16) {
    float* slot = partial + (size_t)(blockIdx.x & 31) * 64;
    atomicAdd(slot + t * 4 + 0, s[t].x);
    atomicAdd(slot + t * 4 + 1, s[t].y);
    atomicAdd(slot + t * 4 + 2, s[t].z);
    atomicAdd(slot + t * 4 + 3, s[t].w);
  }
}

__global__ __launch_bounds__(64) void mean_finish(const float* __restrict__ partial,
                                                  float* __restrict__ out, int n) {
  const int c = threadIdx.x;
  float s = 0.f;
  #pragma unroll
  for (int k = 0; k < 32; ++k) s += partial[k * 64 + c];
  out[c] = s / (float)n;
}

extern "C" void kernel_launch(void* const* d_in, const int* in_sizes, int n_in,
                              void* d_out, int out_size, void* d_ws, size_t ws_size,
                              hipStream_t stream) {
  const float* pose = (const float*)d_in[0];
  const float* w_pos = (const float*)d_in[1];
  const float* b_pos = (const float*)d_in[2];
  const float* w_fc  = (const float*)d_in[3];
  const float* b_fc  = (const float*)d_in[4];
  const float* w_g1  = (const float*)d_in[5];
  const float* b_g1  = (const float*)d_in[6];
  const float* w_g2  = (const float*)d_in[7];
  const float* b_g2  = (const float*)d_in[8];
  const float* w_g3  = (const float*)d_in[9];
  const float* b_g3  = (const float*)d_in[10];
  const int*   edges = (const int*)d_in[11];

  const int n = in_sizes[0] / 64;   // N_NODES
  const int E = in_sizes[11] / 2;   // N_EDGES
  const int* rows = edges;
  const int* cols = edges + E;
  const int NB = (n + 511) >> 9;

  char* p = (char*)d_ws;
  auto alloc = [&](size_t bytes) { char* q = p; p += (bytes + 255) & ~(size_t)255; return q; };
  int*   off     = (int*)  alloc((size_t)n * 4);
  int*   deg     = (int*)  alloc((size_t)n * 4);
  int*   misc    = (int*)  alloc((256 + 2048) * 4);
  int*   gcur    = misc;
  float* partial = (float*)(misc + 256);
  float* dis     = (float*)alloc((size_t)n * 4);
  u16* wp_pos_h = (u16*)alloc(1024 * 16);
  u16* wp_pos_l = (u16*)alloc(1024 * 16);
  u16* wp_fc_h  = (u16*)alloc(2048 * 16);
  u16* wp_fc_l  = (u16*)alloc(2048 * 16);
  u16* wp_g1_h  = (u16*)alloc(2048 * 16);
  u16* wp_g1_l  = (u16*)alloc(2048 * 16);
  u16* wp_g2_h  = (u16*)alloc(2048 * 16);
  u16* wp_g2_l  = (u16*)alloc(2048 * 16);
  u16* wp_g3_h  = (u16*)alloc(1024 * 16);
  u16* wp_g3_l  = (u16*)alloc(1024 * 16);
  int*   csr     = (int*)  alloc((size_t)NB * SLOT * 4);
  size_t bufA_sz = (size_t)NB * SLOT * 4;
  size_t act_sz  = (size_t)n * 128;
  if (act_sz > bufA_sz) bufA_sz = act_sz;
  u8*    bufA    = (u8*)   alloc(bufA_sz);
  u16*   bufB    = (u16*)  alloc((size_t)n * 128 * 2);
  u32*   tmp     = (u32*)bufA;

  const int eb4k         = (E + 4095) / 4096;
  const int ref_blocks   = (n + 63) / 64;
  const int conv_blocks  = (n + 127) / 128;
  const int g_blocks     = (n + 15) / 16;

  // ---- 1: weight packs + misc zeroing ----
  pack_all<<<32, 256, 0, stream>>>(w_pos, w_fc, w_g1, w_g2, w_g3,
      wp_pos_h, wp_pos_l, wp_fc_h, wp_fc_l, wp_g1_h, wp_g1_l,
      wp_g2_h, wp_g2_l, wp_g3_h, wp_g3_l, misc);

  // ---- 2: MERGED bin_pass || refine_fused ----
  bin_and_refine<<<eb4k + ref_blocks, 256, 0, stream>>>(
      rows, cols, gcur, tmp, E, NB, eb4k,
      pose, wp_pos_h, wp_pos_l, b_pos, wp_fc_h, wp_fc_l, b_fc, bufB, n);

  // ---- 3: CSR pass B ----
  bucket_csr<<<NB, 256, 0, stream>>>(tmp, gcur, off, deg, dis, csr, n);

  // ---- conv1 ----
  gemm_conv<128, 128><<<conv_blocks, 256, 0, stream>>>(bufB, wp_g1_h, wp_g1_l, dis, bufA, n);
  gather_f8_128<<<g_blocks, 256, 0, stream>>>(csr, off, deg, bufA, dis, b_g1, bufB, n);

  // ---- conv2 ----
  gemm_conv<128, 128><<<conv_blocks, 256, 0, stream>>>(bufB, wp_g2_h, wp_g2_l, dis, bufA, n);
  gather_f8_128<<<g_blocks, 256, 0, stream>>>(csr, off, deg, bufA, dis, b_g2, bufB, n);

  // ---- conv3 + mean ----
  gemm_conv<128, 64><<<conv_blocks, 256, 0, stream>>>(bufB, wp_g3_h, wp_g3_l, dis, bufA, n);
  gather_mean_part<<<g_blocks, 256, 0, stream>>>(csr, off, deg, bufA, dis, b_g3, partial, n);
  mean_finish<<<1, 64, 0, stream>>>(partial, (float*)d_out, n);
}